// Round 4
// baseline (441.642 us; speedup 1.0000x reference)
//
#include <hip/hip_runtime.h>

// 2-layer LSTM (H=50, I=7), B=4096, T=256, + FC head. fp32 in/out.
// Round 4: 2 blocks/CU. NB=8 batches/block, grid=512, block=512 (8 waves).
// Two independent blocks co-resident per CU -> 4 waves/SIMD, uncorrelated
// barriers: one block's waves fill the other's barrier/latency stalls (the
// ~45% unfilled stall seen in round 3 at 2 waves/SIMD). MFMA C rows 8..15
// are padding (batch dim 8 < 16) -- masked lanes burn the same instr slots,
// accepted in exchange for 2x wave-level parallelism.
// Also: activation input scales folded into weights/biases at build time
// (i,f,o rows x -log2e; g rows x -2log2e), so sigmoid = rcp(1+exp2(acc))
// and tanh = 2*rcp(1+exp2(acc))-1 with no per-gate multiply.
// Structure from round 3: layer-split waves (0-3: layer1 @ t=p, 4-7: layer2
// @ t=p-1), shared double-buffered LDS A-shuttle, K=128 layout
//   k 0..49 = h1(p-1) | k 50..99 = h2(p-2) | k 100..106 = x(p) | else 0,
// one __syncthreads per phase, biases folded into MFMA C-init.

#define T_SEQ 256
#define HID 50
#define INF 7
#define NB 8
#define BLK 512
#define LSTR 144  // shuttle row stride in halves (16B-aligned, spreads banks)

typedef _Float16 f16x8 __attribute__((ext_vector_type(8)));
typedef float f32x4 __attribute__((ext_vector_type(4)));

#define NLOG2E  -1.442695040888963f   // -log2(e)
#define N2LOG2E -2.885390081777927f   // -2*log2(e)

__device__ __forceinline__ float sig_pre(float xs) {
    // input already scaled by -log2e
    return __builtin_amdgcn_rcpf(1.0f + __builtin_amdgcn_exp2f(xs));
}
__device__ __forceinline__ float tanh_pre(float xs) {
    // input already scaled by -2*log2e
    return 2.0f * __builtin_amdgcn_rcpf(1.0f + __builtin_amdgcn_exp2f(xs)) - 1.0f;
}

__global__ __launch_bounds__(BLK, 4) void lstm2_fc_kernel(
    const float* __restrict__ x,
    const float* __restrict__ w_ih0, const float* __restrict__ w_hh0,
    const float* __restrict__ b_ih0, const float* __restrict__ b_hh0,
    const float* __restrict__ w_ih1, const float* __restrict__ w_hh1,
    const float* __restrict__ b_ih1, const float* __restrict__ b_hh1,
    const float* __restrict__ w_fc, const float* __restrict__ b_fc,
    float* __restrict__ out)
{
    __shared__ _Float16 lhs[2][16 * LSTR];  // double-buffered [h1|h2|x] shuttle
    __shared__ float    lgout[16 * 52];     // final h2 (fp32) for FC head

    const int tid   = threadIdx.x;
    const int w     = tid >> 6;      // wave 0..7
    const int layer = w >> 2;        // 0: layer-1 group, 1: layer-2 group
    const int wl    = w & 3;         // unit-group within layer
    const int lane  = tid & 63;
    const int n0    = lane & 15;     // MFMA col-within-tile / A row m
    const int mq    = lane >> 4;     // quad: A k-block, C row-block
    const int u     = wl * 16 + n0;  // hidden unit owned by this lane
    const int b0    = blockIdx.x * NB;

    // ---- this wave's layer's B-fragments: global -> registers (one-time),
    //      with activation scale folded in per gate row ----
    // layer 0: k<50 -> w_hh0 (vs h1), k in [100,107) -> w_ih0 (vs x), else 0
    // layer 1: k<50 -> w_ih1 (vs h1), k in [50,100)  -> w_hh1 (vs h2), else 0
    f16x8 Bf[4][4];
    #pragma unroll
    for (int g = 0; g < 4; ++g) {
        const float gs = (g == 2) ? N2LOG2E : NLOG2E;
        const int r0 = g * HID + u;
        #pragma unroll
        for (int c = 0; c < 4; ++c) {
            #pragma unroll
            for (int j = 0; j < 8; ++j) {
                const int k = c * 32 + mq * 8 + j;
                float v = 0.0f;
                if (u < HID) {
                    if (layer == 0) {
                        if (k < 50)                   v = w_hh0[r0 * 50 + k];
                        else if (k >= 100 && k < 107) v = w_ih0[r0 * 7 + (k - 100)];
                    } else {
                        if (k < 50)                   v = w_ih1[r0 * 50 + k];
                        else if (k < 100)             v = w_hh1[r0 * 50 + (k - 50)];
                    }
                }
                Bf[g][c][j] = (_Float16)(v * gs);
            }
        }
    }

    float bias[4];
    #pragma unroll
    for (int g = 0; g < 4; ++g) {
        const float gs = (g == 2) ? N2LOG2E : NLOG2E;
        if (u < HID)
            bias[g] = gs * ((layer == 0) ? (b_ih0[g * HID + u] + b_hh0[g * HID + u])
                                         : (b_ih1[g * HID + u] + b_hh1[g * HID + u]));
        else bias[g] = 0.0f;
    }

    // ---- init shuttle (zeros = h(-1)=0) + stage x(0) ----
    for (int i = tid; i < 2 * 16 * LSTR; i += BLK) (&lhs[0][0])[i] = (_Float16)0.0f;
    __syncthreads();
    if (tid < NB * INF) {
        const int m = tid / INF, kk = tid - m * INF;
        lhs[0][m * LSTR + 100 + kk] = (_Float16)x[(b0 + m) * (T_SEQ * INF) + kk];
    }
    __syncthreads();

    float cst[4] = {0, 0, 0, 0};  // this lane's cell state (its layer)

    const int kk3 = lane & 7, m3 = lane >> 3;  // x-prefetch mapping (wave 7)
    const long xstride = (long)(T_SEQ * INF);

    // Phase p: layer-1 waves compute t=p (p<256); layer-2 waves t=p-1 (p>=1).
    for (int p = 0; p <= T_SEQ; ++p) {
        const int rb = p & 1, wbuf = rb ^ 1;

        // prefetch x(p+1) early (consumed late-phase; latency hidden)
        float xv0 = 0.0f;
        const bool stage = (w == 7) && (p + 1 < T_SEQ) && (kk3 < INF);
        if (stage)
            xv0 = x[(b0 + m3) * xstride + (p + 1) * INF + kk3];

        // shared A-fragments: [h1(p-1) | h2(p-2) | x(p) | 0]
        f16x8 a[4];
        #pragma unroll
        for (int c = 0; c < 4; ++c)
            a[c] = *reinterpret_cast<const f16x8*>(&lhs[rb][n0 * LSTR + c * 32 + mq * 8]);

        const bool active = (layer == 0) ? (p < T_SEQ) : (p >= 1);
        if (active) {
            f32x4 acc[4];
            #pragma unroll
            for (int g = 0; g < 4; ++g) {
                acc[g] = (f32x4){bias[g], bias[g], bias[g], bias[g]};
                #pragma unroll
                for (int c = 0; c < 4; ++c)
                    acc[g] = __builtin_amdgcn_mfma_f32_16x16x32_f16(a[c], Bf[g][c], acc[g], 0, 0, 0);
            }
            // cell update; rows m = mq*4+r (m >= 8 are padding -> harmless,
            // provably finite: |ct| grows at most linearly, exp2/rcp saturate)
            #pragma unroll
            for (int r = 0; r < 4; ++r) {
                const float si = sig_pre(acc[0][r]);
                const float sf = sig_pre(acc[1][r]);
                const float tg = tanh_pre(acc[2][r]);
                const float so = sig_pre(acc[3][r]);
                const float ct = sf * cst[r] + si * tg;
                cst[r] = ct;
                const float h = so * tanh_pre(ct * N2LOG2E);
                if (u < HID) {
                    const int m = mq * 4 + r;
                    lhs[wbuf][m * LSTR + layer * 50 + u] = (_Float16)h;
                    if (layer == 1 && p == T_SEQ) lgout[m * 52 + u] = h;
                }
            }
        }
        if (stage)
            lhs[wbuf][m3 * LSTR + 100 + kk3] = (_Float16)xv0;
        __syncthreads();  // the ONLY barrier per phase
    }

    // ---- FC head: out = h2(T-1) @ w_fc^T + b_fc ----
    if (tid < NB * INF) {
        const int m = tid / INF, o = tid - m * INF;
        float acc = b_fc[o];
        #pragma unroll
        for (int uu = 0; uu < HID; ++uu)
            acc += w_fc[o * HID + uu] * lgout[m * 52 + uu];
        out[(b0 + m) * INF + o] = acc;
    }
}

extern "C" void kernel_launch(void* const* d_in, const int* in_sizes, int n_in,
                              void* d_out, int out_size, void* d_ws, size_t ws_size,
                              hipStream_t stream) {
    const float* x     = (const float*)d_in[0];
    const float* w_ih0 = (const float*)d_in[1];
    const float* w_hh0 = (const float*)d_in[2];
    const float* b_ih0 = (const float*)d_in[3];
    const float* b_hh0 = (const float*)d_in[4];
    const float* w_ih1 = (const float*)d_in[5];
    const float* w_hh1 = (const float*)d_in[6];
    const float* b_ih1 = (const float*)d_in[7];
    const float* b_hh1 = (const float*)d_in[8];
    const float* w_fc  = (const float*)d_in[9];
    const float* b_fc  = (const float*)d_in[10];
    float* out = (float*)d_out;

    dim3 grid(4096 / NB), block(BLK);
    lstm2_fc_kernel<<<grid, block, 0, stream>>>(
        x, w_ih0, w_hh0, b_ih0, b_hh0, w_ih1, w_hh1, b_ih1, b_hh1, w_fc, b_fc, out);
}

// Round 5
// 384.921 us; speedup vs baseline: 1.1474x; 1.1474x over previous
//
#include <hip/hip_runtime.h>

// 2-layer LSTM (H=50, I=7), B=4096, T=256, + FC head. fp32 in/out.
// Round 5: gate-split wave specialization. grid=256, block=1024 (16 waves,
// 4/SIMD, 1 block/CU). Wave = (layer L, gate-pair gp, unit-group wl):
//   L=w>>3, gp=(w>>2)&1, wl=w&3. Each wave computes 2 gates for its 16 units
//   x 16 batches (L0: 2 K-chunks [h1|x] -> 4 MFMAs; L1: 4 K-chunks
//   [h1|pad|h2] -> 8 MFMAs), writes gate planes to padded LDS exchange G
//   (b128, MPAD=20 spreads banks), barrier, then EVERY lane updates 2 batch
//   rows (m0=gp*8+mq*2) of unit u=16wl+n0 -> 20 trans/lane (round3: 40),
//   writes h to the (now single-buffered) shuttle, barrier.
// Work per lane ~halves while wave density doubles vs round 3; round 4's
// mistake (duplicated work for fill) is avoided -- all 16 waves carry
// distinct work. Phases p: L0 computes t=p (p<256), L1 t=p-1 (p>=1).
// Shuttle K layout: k 0..49 = h1 | 50..56 = x | 64..113 = h2 | else 0.
// Activation scales folded into weights/biases (i,f,o: -log2e; g: -2log2e).

#define T_SEQ 256
#define HID 50
#define INF 7
#define NB 16
#define BLK 1024
#define LSTR 144   // shuttle row stride (halves); measured-OK conflicts in r3
#define MPAD 20    // exchange m-stride (floats): 16B-aligned b128, bank-spread

typedef _Float16 f16x8 __attribute__((ext_vector_type(8)));
typedef float f32x4 __attribute__((ext_vector_type(4)));
typedef float f32x2 __attribute__((ext_vector_type(2)));

#define NLOG2E  -1.442695040888963f   // -log2(e)
#define N2LOG2E -2.885390081777927f   // -2*log2(e)

__device__ __forceinline__ float sig_pre(float xs) {
    return __builtin_amdgcn_rcpf(1.0f + __builtin_amdgcn_exp2f(xs));
}
__device__ __forceinline__ float tanh_pre(float xs) {
    return 2.0f * __builtin_amdgcn_rcpf(1.0f + __builtin_amdgcn_exp2f(xs)) - 1.0f;
}

__global__ __launch_bounds__(BLK, 4) void lstm2_fc_kernel(
    const float* __restrict__ x,
    const float* __restrict__ w_ih0, const float* __restrict__ w_hh0,
    const float* __restrict__ b_ih0, const float* __restrict__ b_hh0,
    const float* __restrict__ w_ih1, const float* __restrict__ w_hh1,
    const float* __restrict__ b_ih1, const float* __restrict__ b_hh1,
    const float* __restrict__ w_fc, const float* __restrict__ b_fc,
    float* __restrict__ out)
{
    __shared__ _Float16 lhs[16 * LSTR];            // single-buffered shuttle
    __shared__ float    G[2 * 4 * 4 * 16 * MPAD];  // [L][wl][g][n0][m<MPAD>]
    __shared__ float    lgout[16 * 52];            // final h2 for FC head

    const int tid  = threadIdx.x;
    const int w    = tid >> 6;       // wave 0..15
    const int L    = w >> 3;         // layer
    const int gp   = (w >> 2) & 1;   // gate-pair: gates {2gp, 2gp+1}
    const int wl   = w & 3;          // unit-group
    const int lane = tid & 63;
    const int n0   = lane & 15;      // MFMA A-row m / C col n
    const int mq   = lane >> 4;      // quad
    const int u    = wl * 16 + n0;   // unit owned (col); real iff u<50
    const int b0   = blockIdx.x * NB;
    const int m0   = gp * 8 + mq * 2;  // first of this lane's 2 update rows

    // ---- B-fragments for this wave's 2 gates (scale folded) ----
    // L0: k<50 -> w_hh0, k in [50,57) -> w_ih0, else 0 (chunks 2,3 zero)
    // L1: k<50 -> w_ih1, k in [64,114) -> w_hh1, else 0
    f16x8 Bf[2][4];
    float bias[2];
    #pragma unroll
    for (int gi = 0; gi < 2; ++gi) {
        const int g = gp * 2 + gi;
        const float gs = (g == 2) ? N2LOG2E : NLOG2E;
        const int r0 = g * HID + u;
        #pragma unroll
        for (int c = 0; c < 4; ++c) {
            #pragma unroll
            for (int j = 0; j < 8; ++j) {
                const int k = c * 32 + mq * 8 + j;
                float v = 0.0f;
                if (u < HID) {
                    if (L == 0) {
                        if (k < 50)                  v = w_hh0[r0 * 50 + k];
                        else if (k < 57)             v = w_ih0[r0 * 7 + (k - 50)];
                    } else {
                        if (k < 50)                  v = w_ih1[r0 * 50 + k];
                        else if (k >= 64 && k < 114) v = w_hh1[r0 * 50 + (k - 64)];
                    }
                }
                Bf[gi][c][j] = (_Float16)(v * gs);
            }
        }
        bias[gi] = (u < HID)
            ? gs * ((L == 0) ? (b_ih0[g * HID + u] + b_hh0[g * HID + u])
                             : (b_ih1[g * HID + u] + b_hh1[g * HID + u]))
            : 0.0f;
    }

    // ---- init shuttle + stage x(0) ----
    for (int i = tid; i < 16 * LSTR; i += BLK) lhs[i] = (_Float16)0.0f;
    __syncthreads();
    if (tid < NB * INF) {
        const int m = tid / INF, kk = tid - m * INF;
        lhs[m * LSTR + 50 + kk] = (_Float16)x[(b0 + m) * (T_SEQ * INF) + kk];
    }
    __syncthreads();

    float cst[2] = {0.0f, 0.0f};   // cell state for this lane's 2 rows

    const int kk3 = lane & 7, m3 = lane >> 3;  // x-prefetch mapping (wave 15)
    const long xstride = (long)(T_SEQ * INF);
    const int gbase0 = ((L * 4 + wl) * 4) * 16 * MPAD;  // this (L,wl)'s G block

    for (int p = 0; p <= T_SEQ; ++p) {
        const bool act = (L == 0) ? (p < T_SEQ) : (p >= 1);

        // prefetch x(p+1) (written to shuttle after b#1)
        float xv0 = 0.0f, xv1 = 0.0f;
        const bool stage = (w == 15) && (p + 1 < T_SEQ) && (kk3 < INF);
        if (stage) {
            xv0 = x[(b0 + m3) * xstride + (p + 1) * INF + kk3];
            xv1 = x[(b0 + m3 + 8) * xstride + (p + 1) * INF + kk3];
        }

        if (act) {
            f32x4 acc[2];
            #pragma unroll
            for (int gi = 0; gi < 2; ++gi)
                acc[gi] = (f32x4){bias[gi], bias[gi], bias[gi], bias[gi]};
            if (L == 0) {
                f16x8 a0 = *reinterpret_cast<const f16x8*>(&lhs[n0 * LSTR + 0 * 32 + mq * 8]);
                f16x8 a1 = *reinterpret_cast<const f16x8*>(&lhs[n0 * LSTR + 1 * 32 + mq * 8]);
                #pragma unroll
                for (int gi = 0; gi < 2; ++gi) {
                    acc[gi] = __builtin_amdgcn_mfma_f32_16x16x32_f16(a0, Bf[gi][0], acc[gi], 0, 0, 0);
                    acc[gi] = __builtin_amdgcn_mfma_f32_16x16x32_f16(a1, Bf[gi][1], acc[gi], 0, 0, 0);
                }
            } else {
                f16x8 a[4];
                #pragma unroll
                for (int c = 0; c < 4; ++c)
                    a[c] = *reinterpret_cast<const f16x8*>(&lhs[n0 * LSTR + c * 32 + mq * 8]);
                #pragma unroll
                for (int gi = 0; gi < 2; ++gi)
                    #pragma unroll
                    for (int c = 0; c < 4; ++c)
                        acc[gi] = __builtin_amdgcn_mfma_f32_16x16x32_f16(a[c], Bf[gi][c], acc[gi], 0, 0, 0);
            }
            // publish 2 gate planes: G[..][g][n0][m], f32x4 over m=mq*4..+3
            #pragma unroll
            for (int gi = 0; gi < 2; ++gi) {
                const int g = gp * 2 + gi;
                *reinterpret_cast<f32x4*>(&G[gbase0 + (g * 16 + n0) * MPAD + mq * 4]) = acc[gi];
            }
        }
        __syncthreads();  // b#1: gates visible; shuttle reads of phase done

        if (act) {
            f32x2 gv[4];
            #pragma unroll
            for (int g = 0; g < 4; ++g)
                gv[g] = *reinterpret_cast<const f32x2*>(&G[gbase0 + (g * 16 + n0) * MPAD + m0]);
            #pragma unroll
            for (int d = 0; d < 2; ++d) {
                const float si = sig_pre(gv[0][d]);
                const float sf = sig_pre(gv[1][d]);
                const float tg = tanh_pre(gv[2][d]);
                const float so = sig_pre(gv[3][d]);
                const float ct = sf * cst[d] + si * tg;
                cst[d] = ct;
                const float h = so * tanh_pre(ct * N2LOG2E);
                if (u < HID) {
                    lhs[(m0 + d) * LSTR + L * 64 + u] = (_Float16)h;
                    if (L == 1 && p == T_SEQ) lgout[(m0 + d) * 52 + u] = h;
                }
            }
        }
        if (stage) {
            lhs[m3 * LSTR + 50 + kk3]       = (_Float16)xv0;
            lhs[(m3 + 8) * LSTR + 50 + kk3] = (_Float16)xv1;
        }
        __syncthreads();  // b#2: h(t) visible for next phase's MFMA reads
    }

    // ---- FC head: out = h2(T-1) @ w_fc^T + b_fc ----
    if (tid < NB * INF) {
        const int m = tid / INF, o = tid - m * INF;
        float acc = b_fc[o];
        #pragma unroll
        for (int uu = 0; uu < HID; ++uu)
            acc += w_fc[o * HID + uu] * lgout[m * 52 + uu];
        out[(b0 + m) * INF + o] = acc;
    }
}

extern "C" void kernel_launch(void* const* d_in, const int* in_sizes, int n_in,
                              void* d_out, int out_size, void* d_ws, size_t ws_size,
                              hipStream_t stream) {
    const float* x     = (const float*)d_in[0];
    const float* w_ih0 = (const float*)d_in[1];
    const float* w_hh0 = (const float*)d_in[2];
    const float* b_ih0 = (const float*)d_in[3];
    const float* b_hh0 = (const float*)d_in[4];
    const float* w_ih1 = (const float*)d_in[5];
    const float* w_hh1 = (const float*)d_in[6];
    const float* b_ih1 = (const float*)d_in[7];
    const float* b_hh1 = (const float*)d_in[8];
    const float* w_fc  = (const float*)d_in[9];
    const float* b_fc  = (const float*)d_in[10];
    float* out = (float*)d_out;

    dim3 grid(4096 / NB), block(BLK);
    lstm2_fc_kernel<<<grid, block, 0, stream>>>(
        x, w_ih0, w_hh0, b_ih0, b_hh0, w_ih1, w_hh1, b_ih1, b_hh1, w_fc, b_fc, out);
}

// Round 6
// 306.386 us; speedup vs baseline: 1.4415x; 1.2563x over previous
//
#include <hip/hip_runtime.h>

// 2-layer LSTM (H=50, I=7), B=4096, T=256, + FC head. fp32 in/out.
// Round 6 = round 3 (best, 270us) + issue-work reduction. grid=256, block=512
// (8 waves, 2/SIMD). Waves 0-3: layer-1 @ t=p (K=64, 8 MFMAs); waves 4-7:
// layer-2 @ t=p-1 (K=128, 16 MFMAs). Wave wl owns all 4 gates of units
// 16wl..16wl+15 (MFMA C-layout col=lane&15, row=(lane>>4)*4+reg) -> cell
// update fully in registers, no exchange. One barrier/phase.
// Shuttle K layout (double-buffered):
//   k 0..49 = h1 | 50..56 = x | 63 = 1.0 | 64..113 = h2 | 127 = 1.0 | else 0
// Biases ride as weight columns against the 1.0 lanes (k63 for L0, k127 for
// L1) -> MFMA C starts from a hoisted zero vector (no per-phase bias movs).
// Gate algebra fused: sig(i)*tanh(g) = (1-B)*rcp((1+A)(1+B)), likewise
// sig(o)*tanh(ct) -> 8 trans/cell (was 10). fminf(arg,80) clamps kill the
// -inf*0=NaN corner; padding-unit lanes have all-zero weights -> acc==0.
// Activation scales folded into weights (i,f,o: -log2e; g: -2log2e).

#define T_SEQ 256
#define HID 50
#define INF 7
#define NB 16
#define BLK 512
#define LSTR 144  // shuttle row stride in halves (16B-aligned)

typedef _Float16 f16x8 __attribute__((ext_vector_type(8)));
typedef float f32x4 __attribute__((ext_vector_type(4)));

#define NLOG2E  -1.442695040888963f   // -log2(e)
#define N2LOG2E -2.885390081777927f   // -2*log2(e)

__global__ __launch_bounds__(BLK, 2) void lstm2_fc_kernel(
    const float* __restrict__ x,
    const float* __restrict__ w_ih0, const float* __restrict__ w_hh0,
    const float* __restrict__ b_ih0, const float* __restrict__ b_hh0,
    const float* __restrict__ w_ih1, const float* __restrict__ w_hh1,
    const float* __restrict__ b_ih1, const float* __restrict__ b_hh1,
    const float* __restrict__ w_fc, const float* __restrict__ b_fc,
    float* __restrict__ out)
{
    __shared__ _Float16 lhs[2][16 * LSTR];  // double-buffered [h1|x|1|h2|1] shuttle
    __shared__ float    lgout[16 * 52];     // final h2 (fp32) for FC head

    const int tid  = threadIdx.x;
    const int w    = tid >> 6;       // wave 0..7
    const int L    = w >> 2;         // 0: layer-1 waves, 1: layer-2 waves
    const int wl   = w & 3;          // unit-group within layer
    const int lane = tid & 63;
    const int n0   = lane & 15;      // MFMA A-row m / C col n
    const int mq   = lane >> 4;      // quad: A k-block, C row-block
    const int u    = wl * 16 + n0;   // hidden unit owned by this lane
    const int b0   = blockIdx.x * NB;

    // ---- B-fragments (scale + bias folded). L0 uses chunks 0-1 only. ----
    // L0: k<50 -> w_hh0 (vs h1), 50..56 -> w_ih0 (vs x), k==63 -> bias (vs 1.0)
    // L1: k<50 -> w_ih1 (vs h1), 64..113 -> w_hh1 (vs h2), k==127 -> bias
    f16x8 Bf[4][4];
    #pragma unroll
    for (int g = 0; g < 4; ++g) {
        const float gs = (g == 2) ? N2LOG2E : NLOG2E;
        const int r0 = g * HID + u;
        #pragma unroll
        for (int c = 0; c < 4; ++c) {
            #pragma unroll
            for (int j = 0; j < 8; ++j) {
                const int k = c * 32 + mq * 8 + j;
                float v = 0.0f;
                if (u < HID) {
                    if (L == 0) {
                        if (k < 50)                  v = w_hh0[r0 * 50 + k];
                        else if (k < 57)             v = w_ih0[r0 * 7 + (k - 50)];
                        else if (k == 63)            v = b_ih0[g * HID + u] + b_hh0[g * HID + u];
                    } else {
                        if (k < 50)                  v = w_ih1[r0 * 50 + k];
                        else if (k >= 64 && k < 114) v = w_hh1[r0 * 50 + (k - 64)];
                        else if (k == 127)           v = b_ih1[g * HID + u] + b_hh1[g * HID + u];
                    }
                }
                Bf[g][c][j] = (_Float16)(v * gs);
            }
        }
    }

    // ---- init shuttle: zeros, 1.0 bias lanes (both buffers), x(0) ----
    for (int i = tid; i < 2 * 16 * LSTR; i += BLK) (&lhs[0][0])[i] = (_Float16)0.0f;
    __syncthreads();
    if (tid < 32) {
        const int m = tid & 15, bsel = tid >> 4;
        lhs[bsel][m * LSTR + 63]  = (_Float16)1.0f;
        lhs[bsel][m * LSTR + 127] = (_Float16)1.0f;
    }
    if (tid < NB * INF) {
        const int m = tid / INF, kk = tid - m * INF;
        lhs[0][m * LSTR + 50 + kk] = (_Float16)x[(b0 + m) * (T_SEQ * INF) + kk];
    }
    __syncthreads();

    float cst[4] = {0.0f, 0.0f, 0.0f, 0.0f};

    const int kk3 = lane & 7, m3 = lane >> 3;  // x-prefetch mapping (wave 3, an L0 wave)
    const long xstride = (long)(T_SEQ * INF);
    const f32x4 zf = {0.0f, 0.0f, 0.0f, 0.0f}; // hoisted zero C-init

    // Phase p: L0 waves compute t=p (p<256); L1 waves t=p-1 (p>=1).
    for (int p = 0; p <= T_SEQ; ++p) {
        const int rb = p & 1, wbuf = rb ^ 1;

        float xv0 = 0.0f, xv1 = 0.0f;
        const bool stage = (w == 3) && (p + 1 < T_SEQ) && (kk3 < INF);
        if (stage) {
            xv0 = x[(b0 + m3) * xstride + (p + 1) * INF + kk3];
            xv1 = x[(b0 + m3 + 8) * xstride + (p + 1) * INF + kk3];
        }

        const bool act = (L == 0) ? (p < T_SEQ) : (p >= 1);
        if (act) {
            f32x4 acc[4];
            if (L == 0) {
                f16x8 a0 = *reinterpret_cast<const f16x8*>(&lhs[rb][n0 * LSTR + mq * 8]);
                f16x8 a1 = *reinterpret_cast<const f16x8*>(&lhs[rb][n0 * LSTR + 32 + mq * 8]);
                #pragma unroll
                for (int g = 0; g < 4; ++g) {
                    acc[g] = __builtin_amdgcn_mfma_f32_16x16x32_f16(a0, Bf[g][0], zf, 0, 0, 0);
                    acc[g] = __builtin_amdgcn_mfma_f32_16x16x32_f16(a1, Bf[g][1], acc[g], 0, 0, 0);
                }
            } else {
                f16x8 a[4];
                #pragma unroll
                for (int c = 0; c < 4; ++c)
                    a[c] = *reinterpret_cast<const f16x8*>(&lhs[rb][n0 * LSTR + c * 32 + mq * 8]);
                #pragma unroll
                for (int g = 0; g < 4; ++g) {
                    acc[g] = __builtin_amdgcn_mfma_f32_16x16x32_f16(a[0], Bf[g][0], zf, 0, 0, 0);
                    #pragma unroll
                    for (int c = 1; c < 4; ++c)
                        acc[g] = __builtin_amdgcn_mfma_f32_16x16x32_f16(a[c], Bf[g][c], acc[g], 0, 0, 0);
                }
            }
            // cell update, fused-rcp algebra (8 trans/cell)
            #pragma unroll
            for (int r = 0; r < 4; ++r) {
                const float eA = __builtin_amdgcn_exp2f(acc[0][r]);               // e^{-i}
                const float eB = __builtin_amdgcn_exp2f(fminf(acc[2][r], 80.0f)); // e^{-2g}
                const float eF = __builtin_amdgcn_exp2f(acc[1][r]);               // e^{-f}
                const float sf   = __builtin_amdgcn_rcpf(1.0f + eF);
                const float sitg = (1.0f - eB) *
                                   __builtin_amdgcn_rcpf((1.0f + eA) * (1.0f + eB));
                const float ct = sf * cst[r] + sitg;
                cst[r] = ct;
                const float eC = __builtin_amdgcn_exp2f(acc[3][r]);               // e^{-o}
                const float eD = __builtin_amdgcn_exp2f(fminf(ct * N2LOG2E, 80.0f)); // e^{-2ct}
                const float h = (1.0f - eD) *
                                __builtin_amdgcn_rcpf((1.0f + eC) * (1.0f + eD));
                if (u < HID) {
                    const int m = mq * 4 + r;
                    lhs[wbuf][m * LSTR + L * 64 + u] = (_Float16)h;
                    if (L == 1 && p == T_SEQ) lgout[m * 52 + u] = h;
                }
            }
        }
        if (stage) {
            lhs[wbuf][m3 * LSTR + 50 + kk3]       = (_Float16)xv0;
            lhs[wbuf][(m3 + 8) * LSTR + 50 + kk3] = (_Float16)xv1;
        }
        __syncthreads();  // the ONLY barrier per phase
    }

    // ---- FC head: out = h2(T-1) @ w_fc^T + b_fc ----
    if (tid < NB * INF) {
        const int m = tid / INF, o = tid - m * INF;
        float acc = b_fc[o];
        #pragma unroll
        for (int uu = 0; uu < HID; ++uu)
            acc += w_fc[o * HID + uu] * lgout[m * 52 + uu];
        out[(b0 + m) * INF + o] = acc;
    }
}

extern "C" void kernel_launch(void* const* d_in, const int* in_sizes, int n_in,
                              void* d_out, int out_size, void* d_ws, size_t ws_size,
                              hipStream_t stream) {
    const float* x     = (const float*)d_in[0];
    const float* w_ih0 = (const float*)d_in[1];
    const float* w_hh0 = (const float*)d_in[2];
    const float* b_ih0 = (const float*)d_in[3];
    const float* b_hh0 = (const float*)d_in[4];
    const float* w_ih1 = (const float*)d_in[5];
    const float* w_hh1 = (const float*)d_in[6];
    const float* b_ih1 = (const float*)d_in[7];
    const float* b_hh1 = (const float*)d_in[8];
    const float* w_fc  = (const float*)d_in[9];
    const float* b_fc  = (const float*)d_in[10];
    float* out = (float*)d_out;

    dim3 grid(4096 / NB), block(BLK);
    lstm2_fc_kernel<<<grid, block, 0, stream>>>(
        x, w_ih0, w_hh0, b_ih0, b_hh0, w_ih1, w_hh1, b_ih1, b_hh1, w_fc, b_fc, out);
}